// Round 6
// baseline (337.353 us; speedup 1.0000x reference)
//
#include <hip/hip_runtime.h>
#include <hip/hip_bf16.h>
#include <cstddef>

#define SEQ     2048
#define BATCH   2
#define DIMSZ   1024
#define HEADS   16
#define HDIM    64
#define E3      3072
#define RESN    512
#define NTAPS   101
#define NFILT   4
#define MROWS   (BATCH * SEQ)   // 4096
#define LOG2E   1.44269504088896340736f

typedef __attribute__((ext_vector_type(8))) short bf16x8;
typedef __attribute__((ext_vector_type(4))) float f32x4;

__device__ __forceinline__ unsigned short f2bf(float f) {
  unsigned u = __float_as_uint(f);
  u += 0x7fffu + ((u >> 16) & 1u);          // RNE
  return (unsigned short)(u >> 16);
}
__device__ __forceinline__ float bf2f(unsigned short h) {
  return __uint_as_float(((unsigned)h) << 16);
}
__device__ __forceinline__ void split2(float f, unsigned short& h, unsigned short& l) {
  h = f2bf(f);
  l = f2bf(f - bf2f(h));
}
// packed f32 pair -> bf16x2 in one u32 (compiler emits v_cvt_pk_bf16_f32)
__device__ __forceinline__ unsigned pkbf(float a, float b) {
  __hip_bfloat162 t = __float22bfloat162_rn(float2{a, b});
  union { __hip_bfloat162 h; unsigned u; } cv; cv.h = t;
  return cv.u;
}
// async global -> LDS, 16B per lane (HW: lds dest = uniform base + lane*16)
__device__ __forceinline__ void async16(void* lds, const void* g) {
  __builtin_amdgcn_global_load_lds(
      (const __attribute__((address_space(1))) unsigned int*)g,
      (__attribute__((address_space(3))) unsigned int*)lds, 16, 0, 0);
}

// ---------------------------------------------------------------------------
// f32 -> bf16 bulk convert (n multiple of 8)
// ---------------------------------------------------------------------------
__global__ __launch_bounds__(256) void cvt_bf16_kern(
    const float* __restrict__ src, unsigned short* __restrict__ dst, int n)
{
  const int i = (blockIdx.x * 256 + threadIdx.x) * 8;
  if (i >= n) return;
  const float4 a = *(const float4*)(src + i);
  const float4 b = *(const float4*)(src + i + 4);
  ushort4 p = {f2bf(a.x), f2bf(a.y), f2bf(a.z), f2bf(a.w)};
  ushort4 q = {f2bf(b.x), f2bf(b.y), f2bf(b.z), f2bf(b.w)};
  *(ushort4*)(dst + i)     = p;
  *(ushort4*)(dst + i + 4) = q;
}

// f32 -> (hi, lo) bf16 pair (n multiple of 4)
__global__ __launch_bounds__(256) void split_pair_kern(
    const float* __restrict__ src, unsigned short* __restrict__ hi,
    unsigned short* __restrict__ lo, int n)
{
  const int i = (blockIdx.x * 256 + threadIdx.x) * 4;
  if (i >= n) return;
  const float4 a = *(const float4*)(src + i);
  ushort4 h, l;
  split2(a.x, h.x, l.x); split2(a.y, h.y, l.y);
  split2(a.z, h.z, l.z); split2(a.w, h.w, l.w);
  *(ushort4*)(hi + i) = h;
  *(ushort4*)(lo + i) = l;
}

// ---------------------------------------------------------------------------
// positional bias (|i-j| table), PRE-SCALED by log2(e) for exp2-domain softmax.
// grid = 16 blocks (one per head).
// ---------------------------------------------------------------------------
__global__ __launch_bounds__(256) void pbias_kernel(
    const float* __restrict__ coeffs, const float* __restrict__ Wpos,
    float* __restrict__ pbias2)
{
  __shared__ float table[RESN][NFILT];
  const int h = blockIdx.x;
  const int tid = threadIdx.x;
  for (int rf = tid; rf < RESN * NFILT; rf += 256) {
    const int r = rf >> 2, f = rf & 3;
    const int tmax = r < (NTAPS - 1) ? r : (NTAPS - 1);
    float s = 0.f;
    for (int t = 0; t <= tmax; ++t)
      s += coeffs[f * NTAPS + t] * ((float)(r - t) * (1.0f / (float)(RESN - 1)));
    table[r][f] = s;
  }
  __syncthreads();
  float wp[NFILT];
#pragma unroll
  for (int f = 0; f < NFILT; ++f) wp[f] = Wpos[h * NFILT + f];
  for (int d = tid; d < SEQ; d += 256) {
    const float rel = (float)d / (float)(SEQ - 1);
    int idx = (int)rintf(rel * (float)(RESN - 1));
    idx = idx < 0 ? 0 : (idx > RESN - 1 ? RESN - 1 : idx);
    float s = 0.f;
#pragma unroll
    for (int f = 0; f < NFILT; ++f) s += table[idx][f] * wp[f];
    pbias2[h * SEQ + d] = s * LOG2E;
  }
}

// ---------------------------------------------------------------------------
// Pure-bf16 MFMA GEMM (m97 structure): C[m][n] = sum_k A[m][k]*B[n][k].
// 128x128 tile, BK=32, linear LDS [128][32] (64B rows -> naturally 8-deep
// uniform reads), global_load_lds width-16 staging, 2 barriers / K-step.
// ---------------------------------------------------------------------------
__global__ __launch_bounds__(256) void gemm_bf16(
    const unsigned short* __restrict__ A, const unsigned short* __restrict__ B,
    unsigned short* __restrict__ C, int M, int N, int K)
{
  __shared__ unsigned short As[128][32];
  __shared__ unsigned short Bs[128][32];
  const int tid = threadIdx.x;
  const int lane = tid & 63;
  const int w = tid >> 6, wm = w >> 1, wn = w & 1;
  const int c = lane & 15, G = lane >> 4;
  const int m0 = blockIdx.y * 128, n0 = blockIdx.x * 128;

  const int srow = lane >> 2;            // 0..15 within wave-chunk
  const int scol = (lane & 3) << 3;      // ushort col 0,8,16,24

  f32x4 acc[4][4];
#pragma unroll
  for (int mf = 0; mf < 4; ++mf)
#pragma unroll
    for (int nf = 0; nf < 4; ++nf) acc[mf][nf] = (f32x4){0.f, 0.f, 0.f, 0.f};

  for (int k0 = 0; k0 < K; k0 += 32) {
    __syncthreads();   // all waves done reading previous tile
#pragma unroll
    for (int r = 0; r < 2; ++r) {
      const int chunk = r * 4 + w;             // 0..7, 16 rows each
      const int row = (chunk << 4) + srow;
      async16(&As[chunk << 4][0], A + (size_t)(m0 + row) * K + k0 + scol);
      async16(&Bs[chunk << 4][0], B + (size_t)(n0 + row) * K + k0 + scol);
    }
    __syncthreads();   // vmcnt(0) drain: staged data visible

    bf16x8 fa[4], fb[4];
#pragma unroll
    for (int mf = 0; mf < 4; ++mf)
      fa[mf] = *(const bf16x8*)&As[wm * 64 + 16 * mf + c][8 * G];
#pragma unroll
    for (int nf = 0; nf < 4; ++nf)
      fb[nf] = *(const bf16x8*)&Bs[wn * 64 + 16 * nf + c][8 * G];
#pragma unroll
    for (int nf = 0; nf < 4; ++nf)
#pragma unroll
      for (int mf = 0; mf < 4; ++mf)
        acc[mf][nf] = __builtin_amdgcn_mfma_f32_16x16x32_bf16(fa[mf], fb[nf], acc[mf][nf], 0, 0, 0);
  }

#pragma unroll
  for (int mf = 0; mf < 4; ++mf)
#pragma unroll
    for (int nf = 0; nf < 4; ++nf)
#pragma unroll
      for (int r = 0; r < 4; ++r)
        C[(size_t)(m0 + wm * 64 + 16 * mf + 4 * G + r) * N + n0 + wn * 64 + 16 * nf + c] =
            f2bf(acc[mf][nf][r]);
}

// ---------------------------------------------------------------------------
// Split-bf16 (3-term) GEMM, same m97 staging structure. 4 LDS tiles (32 KB).
// ---------------------------------------------------------------------------
__global__ __launch_bounds__(256) void gemm_split3(
    const unsigned short* __restrict__ Ah, const unsigned short* __restrict__ Al,
    const unsigned short* __restrict__ Bh, const unsigned short* __restrict__ Bl,
    float* __restrict__ C, int M, int N, int K)
{
  __shared__ unsigned short AhS[128][32], AlS[128][32];
  __shared__ unsigned short BhS[128][32], BlS[128][32];
  const int tid = threadIdx.x;
  const int lane = tid & 63;
  const int w = tid >> 6, wm = w >> 1, wn = w & 1;
  const int c = lane & 15, G = lane >> 4;
  const int m0 = blockIdx.y * 128, n0 = blockIdx.x * 128;

  const int srow = lane >> 2;
  const int scol = (lane & 3) << 3;

  f32x4 acc[4][4];
#pragma unroll
  for (int mf = 0; mf < 4; ++mf)
#pragma unroll
    for (int nf = 0; nf < 4; ++nf) acc[mf][nf] = (f32x4){0.f, 0.f, 0.f, 0.f};

  for (int k0 = 0; k0 < K; k0 += 32) {
    __syncthreads();
#pragma unroll
    for (int r = 0; r < 2; ++r) {
      const int chunk = r * 4 + w;
      const int row = (chunk << 4) + srow;
      const size_t oa = (size_t)(m0 + row) * K + k0 + scol;
      const size_t ob = (size_t)(n0 + row) * K + k0 + scol;
      async16(&AhS[chunk << 4][0], Ah + oa);
      async16(&AlS[chunk << 4][0], Al + oa);
      async16(&BhS[chunk << 4][0], Bh + ob);
      async16(&BlS[chunk << 4][0], Bl + ob);
    }
    __syncthreads();

    bf16x8 fah[4], fal[4];
#pragma unroll
    for (int mf = 0; mf < 4; ++mf) {
      fah[mf] = *(const bf16x8*)&AhS[wm * 64 + 16 * mf + c][8 * G];
      fal[mf] = *(const bf16x8*)&AlS[wm * 64 + 16 * mf + c][8 * G];
    }
#pragma unroll
    for (int nf = 0; nf < 4; ++nf) {
      const bf16x8 fbh = *(const bf16x8*)&BhS[wn * 64 + 16 * nf + c][8 * G];
      const bf16x8 fbl = *(const bf16x8*)&BlS[wn * 64 + 16 * nf + c][8 * G];
#pragma unroll
      for (int mf = 0; mf < 4; ++mf) {
        acc[mf][nf] = __builtin_amdgcn_mfma_f32_16x16x32_bf16(fah[mf], fbh, acc[mf][nf], 0, 0, 0);
        acc[mf][nf] = __builtin_amdgcn_mfma_f32_16x16x32_bf16(fah[mf], fbl, acc[mf][nf], 0, 0, 0);
        acc[mf][nf] = __builtin_amdgcn_mfma_f32_16x16x32_bf16(fal[mf], fbh, acc[mf][nf], 0, 0, 0);
      }
    }
  }

#pragma unroll
  for (int mf = 0; mf < 4; ++mf)
#pragma unroll
    for (int nf = 0; nf < 4; ++nf)
#pragma unroll
      for (int r = 0; r < 4; ++r)
        C[(size_t)(m0 + wm * 64 + 16 * mf + 4 * G + r) * N + n0 + wn * 64 + 16 * nf + c] =
            acc[mf][nf][r];
}

// ---------------------------------------------------------------------------
// Pure-bf16 MFMA flash attention, exp2-domain softmax.
// K: global_load_lds into linear [64][64] with pre-swizzled SOURCE
//    (slot ^= row&7), reads apply same XOR -> 8-deep uniform (full BW).
// V: reg-staged transpose [d][j], slot ^= d&7 (read full BW).
// P: [64][64], slot ^= c&7 on write+read (full BW). Total LDS = 32 KB
//    -> 5 blocks/CU.
// ---------------------------------------------------------------------------
__global__ __launch_bounds__(256) void attn_pure(
    const unsigned short* __restrict__ qkv,   // bf16 (4096,3072)
    const float* __restrict__ pbias2,         // (16,2048) f32, *log2e
    unsigned short* __restrict__ ao_hi,
    unsigned short* __restrict__ ao_lo)
{
  __shared__ unsigned short Kh[64][64];
  __shared__ unsigned short Vh[64][64];
  __shared__ unsigned short Ps[64][64];
  __shared__ float pb[SEQ];

  const int tid = threadIdx.x;
  const int lane = tid & 63;
  const int w = tid >> 6;
  const int c = lane & 15, G = lane >> 4;
  const int bh = blockIdx.y, b = bh >> 4, h = bh & 15;
  const int i0 = blockIdx.x * 64;
  const int i_glob = i0 + w * 16 + c;
  const float scale2 = 0.125f * LOG2E;

  for (int idx = tid * 4; idx < SEQ; idx += 1024)
    *(float4*)&pb[idx] = *(const float4*)(pbias2 + h * SEQ + idx);

  // Q B-fragments direct from global
  bf16x8 qb[2];
#pragma unroll
  for (int ks = 0; ks < 2; ++ks)
    qb[ks] = *(const bf16x8*)(qkv + (size_t)(b * SEQ + i_glob) * E3 + h * HDIM + 32 * ks + 8 * G);

  f32x4 oacc[4];
#pragma unroll
  for (int nf = 0; nf < 4; ++nf) oacc[nf] = (f32x4){0.f, 0.f, 0.f, 0.f};
  float mi = -1e30f, li = 0.f;

  const int vd8 = 8 * (tid & 7);        // V-stage: d-block
  const int vjp = 2 * (tid >> 3);       // j-pair 0..62

  // K-stage geometry: chunk = r*4+w covers rows chunk*8..+8; lane -> row/slot
  const int klrow = lane >> 3;          // row within chunk
  const int klsl  = lane & 7;           // LDS 16B slot

  for (int jt = 0; jt < SEQ / 64; ++jt) {
    const int j0 = jt * 64;
    const size_t rowK = (size_t)(b * SEQ + j0) * E3 + DIMSZ + h * HDIM;
    const size_t rowV = (size_t)(b * SEQ + j0) * E3 + 2 * DIMSZ + h * HDIM;

    // V reg loads issued before the barrier (overlap prev compute tail)
    const bf16x8 v0 = *(const bf16x8*)(qkv + rowV + (size_t)vjp * E3 + vd8);
    const bf16x8 v1 = *(const bf16x8*)(qkv + rowV + (size_t)(vjp + 1) * E3 + vd8);

    __syncthreads();   // all waves done reading prev K/V/LDS

    // K async stage: LDS linear, SOURCE pre-swizzled (slot ^= row&7)
#pragma unroll
    for (int r = 0; r < 2; ++r) {
      const int chunk = r * 4 + w;
      const int krow = (chunk << 3) + klrow;
      const int ksl = klsl ^ (krow & 7);
      async16(&Kh[chunk << 3][0], qkv + rowK + (size_t)krow * E3 + 8 * ksl);
    }
    // V scatter-transpose writes (swizzle: slot ^= d&7)
#pragma unroll
    for (int e = 0; e < 8; ++e) {
      const int d = vd8 + e;
      const unsigned pk = (unsigned)(unsigned short)v0[e] |
                          ((unsigned)(unsigned short)v1[e] << 16);
      const int col = (((vjp >> 3) ^ (d & 7)) << 3) | (vjp & 7);
      *(unsigned*)&Vh[d][col] = pk;
    }
    __syncthreads();   // drains K gloads (vmcnt) + V writes (lgkm)

    // ---- S^T = K * Q^T (K read with XOR swizzle) ----
    f32x4 st[4];
#pragma unroll
    for (int mf = 0; mf < 4; ++mf) st[mf] = (f32x4){0.f, 0.f, 0.f, 0.f};
#pragma unroll
    for (int ks = 0; ks < 2; ++ks)
#pragma unroll
      for (int mf = 0; mf < 4; ++mf) {
        const int sr = (4 * ks + G) ^ (c & 7);   // row&7 == c&7
        const bf16x8 ka = *(const bf16x8*)&Kh[16 * mf + c][8 * sr];
        st[mf] = __builtin_amdgcn_mfma_f32_16x16x32_bf16(ka, qb[ks], st[mf], 0, 0, 0);
      }

    // ---- online softmax (exp2 domain); lane holds 16 logits of row i_glob --
    float p[16];
    float rm = -1e30f;
#pragma unroll
    for (int mf = 0; mf < 4; ++mf)
#pragma unroll
      for (int r = 0; r < 4; ++r) {
        const int j = j0 + 16 * mf + 4 * G + r;
        const int d = i_glob > j ? i_glob - j : j - i_glob;
        const float lg = fmaf(st[mf][r], scale2, pb[d]);
        p[mf * 4 + r] = lg;
        rm = fmaxf(rm, lg);
      }
    rm = fmaxf(rm, __shfl_xor(rm, 16));
    rm = fmaxf(rm, __shfl_xor(rm, 32));
    const float newm = fmaxf(mi, rm);
    const float fr = exp2f(mi - newm);
    float rs = 0.f;
#pragma unroll
    for (int t = 0; t < 16; ++t) {
      p[t] = exp2f(p[t] - newm);
      rs += p[t];
    }
    rs += __shfl_xor(rs, 16);
    rs += __shfl_xor(rs, 32);
    li = li * fr + rs;
    mi = newm;
    float frr[4];
#pragma unroll
    for (int r = 0; r < 4; ++r) frr[r] = __shfl(fr, 20 * G + r);
#pragma unroll
    for (int nf = 0; nf < 4; ++nf)
#pragma unroll
      for (int r = 0; r < 4; ++r) oacc[nf][r] *= frr[r];

    // ---- stage P bf16 (packed cvt), slot ^= c&7 ----
#pragma unroll
    for (int mf = 0; mf < 4; ++mf) {
      const int sw = (2 * mf + (G >> 1)) ^ (c & 7);
      uint2 pw = {pkbf(p[4 * mf + 0], p[4 * mf + 1]),
                  pkbf(p[4 * mf + 2], p[4 * mf + 3])};
      *(uint2*)&Ps[16 * w + c][8 * sw + 4 * (G & 1)] = pw;
    }

    // ---- O += P V (same-wave P read; swizzled) ----
#pragma unroll
    for (int ks = 0; ks < 2; ++ks) {
      const int spr = (4 * ks + G) ^ (c & 7);
      const bf16x8 pa = *(const bf16x8*)&Ps[16 * w + c][8 * spr];
#pragma unroll
      for (int nf = 0; nf < 4; ++nf) {
        const int d = 16 * nf + c;
        const int sv = (4 * ks + G) ^ (d & 7);
        const bf16x8 vb = *(const bf16x8*)&Vh[d][8 * sv];
        oacc[nf] = __builtin_amdgcn_mfma_f32_16x16x32_bf16(pa, vb, oacc[nf], 0, 0, 0);
      }
    }
  }

  // epilogue
  float rinv[4];
#pragma unroll
  for (int r = 0; r < 4; ++r) rinv[r] = 1.0f / __shfl(li, 20 * G + r);
#pragma unroll
  for (int nf = 0; nf < 4; ++nf)
#pragma unroll
    for (int r = 0; r < 4; ++r) {
      const float v = oacc[nf][r] * rinv[r];
      const size_t off = (size_t)(b * SEQ + i0 + 16 * w + 4 * G + r) * DIMSZ +
                         h * HDIM + 16 * nf + c;
      unsigned short vh, vl;
      split2(v, vh, vl);
      ao_hi[off] = vh;
      ao_lo[off] = vl;
    }
}

// ---------------------------------------------------------------------------
extern "C" void kernel_launch(void* const* d_in, const int* in_sizes, int n_in,
                              void* d_out, int out_size, void* d_ws, size_t ws_size,
                              hipStream_t stream) {
  const float* x      = (const float*)d_in[0];
  const float* Wqkv   = (const float*)d_in[1];
  const float* Wout   = (const float*)d_in[2];
  const float* Wpos   = (const float*)d_in[3];
  const float* coeffs = (const float*)d_in[4];
  float* out = (float*)d_out;

  unsigned short* qkv_bf  = (unsigned short*)d_ws;           // 4096*3072
  unsigned short* x_bf    = qkv_bf + (size_t)MROWS * E3;     // 4096*1024
  unsigned short* wqkv_bf = x_bf + (size_t)MROWS * DIMSZ;    // 3072*1024
  unsigned short* wout_h  = wqkv_bf + (size_t)E3 * DIMSZ;    // 1024*1024
  unsigned short* wout_l  = wout_h + (size_t)DIMSZ * DIMSZ;
  unsigned short* ao_h    = wout_l + (size_t)DIMSZ * DIMSZ;  // 4096*1024
  unsigned short* ao_l    = ao_h + (size_t)MROWS * DIMSZ;
  float* pbias2 = (float*)(ao_l + (size_t)MROWS * DIMSZ);    // 16*2048

  const int nx = MROWS * DIMSZ;
  const int nw = E3 * DIMSZ;
  const int no = DIMSZ * DIMSZ;

  cvt_bf16_kern<<<nx / 2048, 256, 0, stream>>>(x, x_bf, nx);
  cvt_bf16_kern<<<nw / 2048, 256, 0, stream>>>(Wqkv, wqkv_bf, nw);
  split_pair_kern<<<no / 1024, 256, 0, stream>>>(Wout, wout_h, wout_l, no);
  pbias_kernel<<<HEADS, 256, 0, stream>>>(coeffs, Wpos, pbias2);

  dim3 g1(E3 / 128, MROWS / 128);
  gemm_bf16<<<g1, 256, 0, stream>>>(x_bf, wqkv_bf, qkv_bf, MROWS, E3, DIMSZ);

  dim3 g2(SEQ / 64, BATCH * HEADS);
  attn_pure<<<g2, 256, 0, stream>>>(qkv_bf, pbias2, ao_h, ao_l);

  dim3 g3(DIMSZ / 128, MROWS / 128);
  gemm_split3<<<g3, 256, 0, stream>>>(ao_h, ao_l, wout_h, wout_l, out, MROWS, DIMSZ, DIMSZ);
}

// Round 8
// 318.064 us; speedup vs baseline: 1.0606x; 1.0606x over previous
//
#include <hip/hip_runtime.h>
#include <hip/hip_bf16.h>
#include <cstddef>

#define SEQ     2048
#define BATCH   2
#define DIMSZ   1024
#define HEADS   16
#define HDIM    64
#define E3      3072
#define RESN    512
#define NTAPS   101
#define NFILT   4
#define MROWS   (BATCH * SEQ)   // 4096
#define LOG2E   1.44269504088896340736f

typedef __attribute__((ext_vector_type(8))) short bf16x8;
typedef __attribute__((ext_vector_type(4))) float f32x4;

__device__ __forceinline__ unsigned short f2bf(float f) {
  unsigned u = __float_as_uint(f);
  u += 0x7fffu + ((u >> 16) & 1u);          // RNE
  return (unsigned short)(u >> 16);
}
__device__ __forceinline__ float bf2f(unsigned short h) {
  return __uint_as_float(((unsigned)h) << 16);
}
__device__ __forceinline__ void split2(float f, unsigned short& h, unsigned short& l) {
  h = f2bf(f);
  l = f2bf(f - bf2f(h));
}
__device__ __forceinline__ unsigned pkbf(float a, float b) {
  __hip_bfloat162 t = __float22bfloat162_rn(float2{a, b});
  union { __hip_bfloat162 h; unsigned u; } cv; cv.h = t;
  return cv.u;
}
__device__ __forceinline__ void async16(void* lds, const void* g) {
  __builtin_amdgcn_global_load_lds(
      (const __attribute__((address_space(1))) unsigned int*)g,
      (__attribute__((address_space(3))) unsigned int*)lds, 16, 0, 0);
}
#define EXP2(x) __builtin_amdgcn_exp2f(x)   // raw v_exp_f32 (2^x)

// ---------------------------------------------------------------------------
__global__ __launch_bounds__(256) void cvt_bf16_kern(
    const float* __restrict__ src, unsigned short* __restrict__ dst, int n)
{
  const int i = (blockIdx.x * 256 + threadIdx.x) * 8;
  if (i >= n) return;
  const float4 a = *(const float4*)(src + i);
  const float4 b = *(const float4*)(src + i + 4);
  ushort4 p = {f2bf(a.x), f2bf(a.y), f2bf(a.z), f2bf(a.w)};
  ushort4 q = {f2bf(b.x), f2bf(b.y), f2bf(b.z), f2bf(b.w)};
  *(ushort4*)(dst + i)     = p;
  *(ushort4*)(dst + i + 4) = q;
}

__global__ __launch_bounds__(256) void split_pair_kern(
    const float* __restrict__ src, unsigned short* __restrict__ hi,
    unsigned short* __restrict__ lo, int n)
{
  const int i = (blockIdx.x * 256 + threadIdx.x) * 4;
  if (i >= n) return;
  const float4 a = *(const float4*)(src + i);
  ushort4 h, l;
  split2(a.x, h.x, l.x); split2(a.y, h.y, l.y);
  split2(a.z, h.z, l.z); split2(a.w, h.w, l.w);
  *(ushort4*)(hi + i) = h;
  *(ushort4*)(lo + i) = l;
}

// ---------------------------------------------------------------------------
// positional bias (|i-j|), pre-scaled by log2e. grid = 16 (one per head).
// ---------------------------------------------------------------------------
__global__ __launch_bounds__(256) void pbias_kernel(
    const float* __restrict__ coeffs, const float* __restrict__ Wpos,
    float* __restrict__ pbias2)
{
  __shared__ float table[RESN][NFILT];
  const int h = blockIdx.x;
  const int tid = threadIdx.x;
  for (int rf = tid; rf < RESN * NFILT; rf += 256) {
    const int r = rf >> 2, f = rf & 3;
    const int tmax = r < (NTAPS - 1) ? r : (NTAPS - 1);
    float s = 0.f;
    for (int t = 0; t <= tmax; ++t)
      s += coeffs[f * NTAPS + t] * ((float)(r - t) * (1.0f / (float)(RESN - 1)));
    table[r][f] = s;
  }
  __syncthreads();
  float wp[NFILT];
#pragma unroll
  for (int f = 0; f < NFILT; ++f) wp[f] = Wpos[h * NFILT + f];
  for (int d = tid; d < SEQ; d += 256) {
    const float rel = (float)d / (float)(SEQ - 1);
    int idx = (int)rintf(rel * (float)(RESN - 1));
    idx = idx < 0 ? 0 : (idx > RESN - 1 ? RESN - 1 : idx);
    float s = 0.f;
#pragma unroll
    for (int f = 0; f < NFILT; ++f) s += table[idx][f] * wp[f];
    pbias2[h * SEQ + d] = s * LOG2E;
  }
}

// ---------------------------------------------------------------------------
// Pure-bf16 GEMM, 128x128 tile, BK=32, DOUBLE-BUFFERED single-barrier K-loop:
// issue next tile's global_load_lds, compute current, one barrier (vmcnt0).
// XCD-aware block swizzle (nwg % 8 == 0). LDS 32 KB.
// ---------------------------------------------------------------------------
__global__ __launch_bounds__(256, 4) void gemm_bf16(
    const unsigned short* __restrict__ A, const unsigned short* __restrict__ B,
    unsigned short* __restrict__ C, int M, int N, int K)
{
  __shared__ unsigned short As[2][128][32];
  __shared__ unsigned short Bs[2][128][32];
  const int tid = threadIdx.x;
  const int lane = tid & 63;
  const int w = tid >> 6, wm = w >> 1, wn = w & 1;
  const int c = lane & 15, G = lane >> 4;

  const int nwg = gridDim.x * gridDim.y;
  const int bid = blockIdx.y * gridDim.x + blockIdx.x;
  const int swz = (bid & 7) * (nwg >> 3) + (bid >> 3);
  const int bx = swz % gridDim.x, by = swz / gridDim.x;
  const int m0 = by * 128, n0 = bx * 128;

  const int srow = lane >> 2;
  const int scol = (lane & 3) << 3;
  const unsigned short* Ab = A + (size_t)m0 * K;
  const unsigned short* Bb = B + (size_t)n0 * K;

  f32x4 acc[4][4];
#pragma unroll
  for (int mf = 0; mf < 4; ++mf)
#pragma unroll
    for (int nf = 0; nf < 4; ++nf) acc[mf][nf] = (f32x4){0.f, 0.f, 0.f, 0.f};

  auto stage = [&](int buf, int k0) {
#pragma unroll
    for (int r = 0; r < 2; ++r) {
      const int chunk = r * 4 + w;
      const int row = (chunk << 4) + srow;
      async16(&As[buf][chunk << 4][0], Ab + (size_t)row * K + k0 + scol);
      async16(&Bs[buf][chunk << 4][0], Bb + (size_t)row * K + k0 + scol);
    }
  };

  stage(0, 0);
  __syncthreads();
  int cur = 0;
  const int NT = K >> 5;
  for (int t = 0; t < NT; ++t) {
    if (t + 1 < NT) stage(cur ^ 1, (t + 1) << 5);
    bf16x8 fa[4], fb[4];
#pragma unroll
    for (int mf = 0; mf < 4; ++mf)
      fa[mf] = *(const bf16x8*)&As[cur][wm * 64 + 16 * mf + c][8 * G];
#pragma unroll
    for (int nf = 0; nf < 4; ++nf)
      fb[nf] = *(const bf16x8*)&Bs[cur][wn * 64 + 16 * nf + c][8 * G];
#pragma unroll
    for (int nf = 0; nf < 4; ++nf)
#pragma unroll
      for (int mf = 0; mf < 4; ++mf)
        acc[mf][nf] = __builtin_amdgcn_mfma_f32_16x16x32_bf16(fa[mf], fb[nf], acc[mf][nf], 0, 0, 0);
    __syncthreads();
    cur ^= 1;
  }

#pragma unroll
  for (int mf = 0; mf < 4; ++mf)
#pragma unroll
    for (int nf = 0; nf < 4; ++nf)
#pragma unroll
      for (int r = 0; r < 4; ++r)
        C[(size_t)(m0 + wm * 64 + 16 * mf + 4 * G + r) * N + n0 + wn * 64 + 16 * nf + c] =
            f2bf(acc[mf][nf][r]);
}

// ---------------------------------------------------------------------------
// Split-bf16 (3-term) GEMM, 64x64 tile (grid 1024 = 4 blocks/CU), BK=32,
// double-buffered single-barrier. LDS = 2 x 16 KB = 32 KB.
// ---------------------------------------------------------------------------
__global__ __launch_bounds__(256, 4) void gemm_split3(
    const unsigned short* __restrict__ Ah, const unsigned short* __restrict__ Al,
    const unsigned short* __restrict__ Bh, const unsigned short* __restrict__ Bl,
    float* __restrict__ C, int M, int N, int K)
{
  __shared__ unsigned short AhS[2][64][32], AlS[2][64][32];
  __shared__ unsigned short BhS[2][64][32], BlS[2][64][32];
  const int tid = threadIdx.x;
  const int lane = tid & 63;
  const int w = tid >> 6, wm = w >> 1, wn = w & 1;
  const int c = lane & 15, G = lane >> 4;

  const int nwg = gridDim.x * gridDim.y;
  const int bid = blockIdx.y * gridDim.x + blockIdx.x;
  const int swz = (bid & 7) * (nwg >> 3) + (bid >> 3);
  const int bx = swz % gridDim.x, by = swz / gridDim.x;
  const int m0 = by * 64, n0 = bx * 64;

  const int srow = lane >> 2;
  const int scol = (lane & 3) << 3;

  f32x4 acc[2][2];
#pragma unroll
  for (int mf = 0; mf < 2; ++mf)
#pragma unroll
    for (int nf = 0; nf < 2; ++nf) acc[mf][nf] = (f32x4){0.f, 0.f, 0.f, 0.f};

  auto stage = [&](int buf, int k0) {
    const int arow = m0 + 16 * w + srow;
    const int brow = n0 + 16 * w + srow;
    async16(&AhS[buf][16 * w][0], Ah + (size_t)arow * K + k0 + scol);
    async16(&AlS[buf][16 * w][0], Al + (size_t)arow * K + k0 + scol);
    async16(&BhS[buf][16 * w][0], Bh + (size_t)brow * K + k0 + scol);
    async16(&BlS[buf][16 * w][0], Bl + (size_t)brow * K + k0 + scol);
  };

  stage(0, 0);
  __syncthreads();
  int cur = 0;
  const int NT = K >> 5;
  for (int t = 0; t < NT; ++t) {
    if (t + 1 < NT) stage(cur ^ 1, (t + 1) << 5);
    bf16x8 fah[2], fal[2], fbh[2], fbl[2];
#pragma unroll
    for (int mf = 0; mf < 2; ++mf) {
      fah[mf] = *(const bf16x8*)&AhS[cur][32 * wm + 16 * mf + c][8 * G];
      fal[mf] = *(const bf16x8*)&AlS[cur][32 * wm + 16 * mf + c][8 * G];
    }
#pragma unroll
    for (int nf = 0; nf < 2; ++nf) {
      fbh[nf] = *(const bf16x8*)&BhS[cur][32 * wn + 16 * nf + c][8 * G];
      fbl[nf] = *(const bf16x8*)&BlS[cur][32 * wn + 16 * nf + c][8 * G];
    }
#pragma unroll
    for (int nf = 0; nf < 2; ++nf)
#pragma unroll
      for (int mf = 0; mf < 2; ++mf) {
        acc[mf][nf] = __builtin_amdgcn_mfma_f32_16x16x32_bf16(fah[mf], fbh[nf], acc[mf][nf], 0, 0, 0);
        acc[mf][nf] = __builtin_amdgcn_mfma_f32_16x16x32_bf16(fah[mf], fbl[nf], acc[mf][nf], 0, 0, 0);
        acc[mf][nf] = __builtin_amdgcn_mfma_f32_16x16x32_bf16(fal[mf], fbh[nf], acc[mf][nf], 0, 0, 0);
      }
    __syncthreads();
    cur ^= 1;
  }

#pragma unroll
  for (int mf = 0; mf < 2; ++mf)
#pragma unroll
    for (int nf = 0; nf < 2; ++nf)
#pragma unroll
      for (int r = 0; r < 4; ++r)
        C[(size_t)(m0 + 32 * wm + 16 * mf + 4 * G + r) * N + n0 + 32 * wn + 16 * nf + c] =
            acc[mf][nf][r];
}

// ---------------------------------------------------------------------------
// Pure-bf16 MFMA flash attention, exp2-domain softmax (v_exp_f32 builtin).
// Same LDS layout as R6 (verified): K async-staged w/ pre-swizzled source,
// V reg-transposed (slot ^= d&7), P [64][64] (slot ^= c&7). 32 KB LDS.
// __launch_bounds__(256,4): VGPR cap 128 (grid caps occupancy at 4 blk/CU).
// ---------------------------------------------------------------------------
__global__ __launch_bounds__(256, 4) void attn_pure(
    const unsigned short* __restrict__ qkv,   // bf16 (4096,3072)
    const float* __restrict__ pbias2,         // (16,2048) f32, *log2e
    unsigned short* __restrict__ ao_hi,
    unsigned short* __restrict__ ao_lo)
{
  __shared__ unsigned short Kh[64][64];
  __shared__ unsigned short Vh[64][64];
  __shared__ unsigned short Ps[64][64];
  __shared__ float pb[SEQ];

  const int tid = threadIdx.x;
  const int lane = tid & 63;
  const int w = tid >> 6;
  const int c = lane & 15, G = lane >> 4;
  const int bh = blockIdx.y, b = bh >> 4, h = bh & 15;
  const int i0 = blockIdx.x * 64;
  const int i_glob = i0 + w * 16 + c;
  const float scale2 = 0.125f * LOG2E;

  for (int idx = tid * 4; idx < SEQ; idx += 1024)
    *(float4*)&pb[idx] = *(const float4*)(pbias2 + h * SEQ + idx);

  bf16x8 qb[2];
#pragma unroll
  for (int ks = 0; ks < 2; ++ks)
    qb[ks] = *(const bf16x8*)(qkv + (size_t)(b * SEQ + i_glob) * E3 + h * HDIM + 32 * ks + 8 * G);

  f32x4 oacc[4];
#pragma unroll
  for (int nf = 0; nf < 4; ++nf) oacc[nf] = (f32x4){0.f, 0.f, 0.f, 0.f};
  float mi = -1e30f, li = 0.f;

  const int vd8 = 8 * (tid & 7);
  const int vjp = 2 * (tid >> 3);
  const int klrow = lane >> 3;
  const int klsl  = lane & 7;

  for (int jt = 0; jt < SEQ / 64; ++jt) {
    const int j0 = jt * 64;
    const size_t rowK = (size_t)(b * SEQ + j0) * E3 + DIMSZ + h * HDIM;
    const size_t rowV = (size_t)(b * SEQ + j0) * E3 + 2 * DIMSZ + h * HDIM;

    const bf16x8 v0 = *(const bf16x8*)(qkv + rowV + (size_t)vjp * E3 + vd8);
    const bf16x8 v1 = *(const bf16x8*)(qkv + rowV + (size_t)(vjp + 1) * E3 + vd8);

    __syncthreads();

#pragma unroll
    for (int r = 0; r < 2; ++r) {
      const int chunk = r * 4 + w;
      const int krow = (chunk << 3) + klrow;
      const int ksl = klsl ^ (krow & 7);
      async16(&Kh[chunk << 3][0], qkv + rowK + (size_t)krow * E3 + 8 * ksl);
    }
#pragma unroll
    for (int e = 0; e < 8; ++e) {
      const int d = vd8 + e;
      const unsigned pk = (unsigned)(unsigned short)v0[e] |
                          ((unsigned)(unsigned short)v1[e] << 16);
      const int col = (((vjp >> 3) ^ (d & 7)) << 3) | (vjp & 7);
      *(unsigned*)&Vh[d][col] = pk;
    }
    __syncthreads();

    // ---- S^T = K * Q^T ----
    f32x4 st[4];
#pragma unroll
    for (int mf = 0; mf < 4; ++mf) st[mf] = (f32x4){0.f, 0.f, 0.f, 0.f};
#pragma unroll
    for (int ks = 0; ks < 2; ++ks)
#pragma unroll
      for (int mf = 0; mf < 4; ++mf) {
        const int sr = (4 * ks + G) ^ (c & 7);
        const bf16x8 ka = *(const bf16x8*)&Kh[16 * mf + c][8 * sr];
        st[mf] = __builtin_amdgcn_mfma_f32_16x16x32_bf16(ka, qb[ks], st[mf], 0, 0, 0);
      }

    // ---- online softmax (exp2 domain) ----
    float p[16];
    float rm = -1e30f;
#pragma unroll
    for (int mf = 0; mf < 4; ++mf)
#pragma unroll
      for (int r = 0; r < 4; ++r) {
        const int j = j0 + 16 * mf + 4 * G + r;
        const int d = i_glob > j ? i_glob - j : j - i_glob;
        const float lg = fmaf(st[mf][r], scale2, pb[d]);
        p[mf * 4 + r] = lg;
        rm = fmaxf(rm, lg);
      }
    rm = fmaxf(rm, __shfl_xor(rm, 16));
    rm = fmaxf(rm, __shfl_xor(rm, 32));
    const float newm = fmaxf(mi, rm);
    const float fr = EXP2(mi - newm);
    float rs = 0.f;
#pragma unroll
    for (int t = 0; t < 16; ++t) {
      p[t] = EXP2(p[t] - newm);
      rs += p[t];
    }
    rs += __shfl_xor(rs, 16);
    rs += __shfl_xor(rs, 32);
    li = li * fr + rs;
    mi = newm;
    float frr[4];
#pragma unroll
    for (int r = 0; r < 4; ++r) frr[r] = __shfl(fr, 20 * G + r);
#pragma unroll
    for (int nf = 0; nf < 4; ++nf)
#pragma unroll
      for (int r = 0; r < 4; ++r) oacc[nf][r] *= frr[r];

    // ---- stage P bf16 (packed cvt), slot ^= c&7 ----
#pragma unroll
    for (int mf = 0; mf < 4; ++mf) {
      const int sw = (2 * mf + (G >> 1)) ^ (c & 7);
      uint2 pw = {pkbf(p[4 * mf + 0], p[4 * mf + 1]),
                  pkbf(p[4 * mf + 2], p[4 * mf + 3])};
      *(uint2*)&Ps[16 * w + c][8 * sw + 4 * (G & 1)] = pw;
    }

    // ---- O += P V ----
#pragma unroll
    for (int ks = 0; ks < 2; ++ks) {
      const int spr = (4 * ks + G) ^ (c & 7);
      const bf16x8 pa = *(const bf16x8*)&Ps[16 * w + c][8 * spr];
#pragma unroll
      for (int nf = 0; nf < 4; ++nf) {
        const int d = 16 * nf + c;
        const int sv = (4 * ks + G) ^ (d & 7);
        const bf16x8 vb = *(const bf16x8*)&Vh[d][8 * sv];
        oacc[nf] = __builtin_amdgcn_mfma_f32_16x16x32_bf16(pa, vb, oacc[nf], 0, 0, 0);
      }
    }
  }

  float rinv[4];
#pragma unroll
  for (int r = 0; r < 4; ++r) rinv[r] = 1.0f / __shfl(li, 20 * G + r);
#pragma unroll
  for (int nf = 0; nf < 4; ++nf)
#pragma unroll
    for (int r = 0; r < 4; ++r) {
      const float v = oacc[nf][r] * rinv[r];
      const size_t off = (size_t)(b * SEQ + i0 + 16 * w + 4 * G + r) * DIMSZ +
                         h * HDIM + 16 * nf + c;
      unsigned short vh, vl;
      split2(v, vh, vl);
      ao_hi[off] = vh;
      ao_lo[off] = vl;
    }
}

// ---------------------------------------------------------------------------
extern "C" void kernel_launch(void* const* d_in, const int* in_sizes, int n_in,
                              void* d_out, int out_size, void* d_ws, size_t ws_size,
                              hipStream_t stream) {
  const float* x      = (const float*)d_in[0];
  const float* Wqkv   = (const float*)d_in[1];
  const float* Wout   = (const float*)d_in[2];
  const float* Wpos   = (const float*)d_in[3];
  const float* coeffs = (const float*)d_in[4];
  float* out = (float*)d_out;

  unsigned short* qkv_bf  = (unsigned short*)d_ws;           // 4096*3072
  unsigned short* x_bf    = qkv_bf + (size_t)MROWS * E3;     // 4096*1024
  unsigned short* wqkv_bf = x_bf + (size_t)MROWS * DIMSZ;    // 3072*1024
  unsigned short* wout_h  = wqkv_bf + (size_t)E3 * DIMSZ;    // 1024*1024
  unsigned short* wout_l  = wout_h + (size_t)DIMSZ * DIMSZ;
  unsigned short* ao_h    = wout_l + (size_t)DIMSZ * DIMSZ;  // 4096*1024
  unsigned short* ao_l    = ao_h + (size_t)MROWS * DIMSZ;
  float* pbias2 = (float*)(ao_l + (size_t)MROWS * DIMSZ);    // 16*2048

  const int nx = MROWS * DIMSZ;
  const int nw = E3 * DIMSZ;
  const int no = DIMSZ * DIMSZ;

  cvt_bf16_kern<<<nx / 2048, 256, 0, stream>>>(x, x_bf, nx);
  cvt_bf16_kern<<<nw / 2048, 256, 0, stream>>>(Wqkv, wqkv_bf, nw);
  split_pair_kern<<<no / 1024, 256, 0, stream>>>(Wout, wout_h, wout_l, no);
  pbias_kernel<<<HEADS, 256, 0, stream>>>(coeffs, Wpos, pbias2);

  dim3 g1(E3 / 128, MROWS / 128);      // 24 x 32 = 768 blocks (%8==0)
  gemm_bf16<<<g1, 256, 0, stream>>>(x_bf, wqkv_bf, qkv_bf, MROWS, E3, DIMSZ);

  dim3 g2(SEQ / 64, BATCH * HEADS);    // 32 x 32 = 1024 blocks
  attn_pure<<<g2, 256, 0, stream>>>(qkv_bf, pbias2, ao_h, ao_l);

  dim3 g3(DIMSZ / 64, MROWS / 64);     // 16 x 64 = 1024 blocks (%8==0)
  gemm_split3<<<g3, 256, 0, stream>>>(ao_h, ao_l, wout_h, wout_l, out, MROWS, DIMSZ, DIMSZ);
}

// Round 9
// 283.380 us; speedup vs baseline: 1.1905x; 1.1224x over previous
//
#include <hip/hip_runtime.h>
#include <hip/hip_bf16.h>
#include <cstddef>

#define SEQ     2048
#define BATCH   2
#define DIMSZ   1024
#define HEADS   16
#define HDIM    64
#define E3      3072
#define RESN    512
#define NTAPS   101
#define NFILT   4
#define MROWS   (BATCH * SEQ)   // 4096
#define LOG2E   1.44269504088896340736f

typedef __attribute__((ext_vector_type(8))) short bf16x8;
typedef __attribute__((ext_vector_type(4))) float f32x4;

__device__ __forceinline__ unsigned short f2bf(float f) {
  unsigned u = __float_as_uint(f);
  u += 0x7fffu + ((u >> 16) & 1u);          // RNE
  return (unsigned short)(u >> 16);
}
__device__ __forceinline__ float bf2f(unsigned short h) {
  return __uint_as_float(((unsigned)h) << 16);
}
__device__ __forceinline__ void split2(float f, unsigned short& h, unsigned short& l) {
  h = f2bf(f);
  l = f2bf(f - bf2f(h));
}
__device__ __forceinline__ unsigned pkbf(float a, float b) {
  __hip_bfloat162 t = __float22bfloat162_rn(float2{a, b});
  union { __hip_bfloat162 h; unsigned u; } cv; cv.h = t;
  return cv.u;
}
__device__ __forceinline__ void async16(void* lds, const void* g) {
  __builtin_amdgcn_global_load_lds(
      (const __attribute__((address_space(1))) unsigned int*)g,
      (__attribute__((address_space(3))) unsigned int*)lds, 16, 0, 0);
}
#define EXP2(x) __builtin_amdgcn_exp2f(x)   // raw v_exp_f32 (2^x)

// ---------------------------------------------------------------------------
__global__ __launch_bounds__(256) void cvt_bf16_kern(
    const float* __restrict__ src, unsigned short* __restrict__ dst, int n)
{
  const int i = (blockIdx.x * 256 + threadIdx.x) * 8;
  if (i >= n) return;
  const float4 a = *(const float4*)(src + i);
  const float4 b = *(const float4*)(src + i + 4);
  ushort4 p = {f2bf(a.x), f2bf(a.y), f2bf(a.z), f2bf(a.w)};
  ushort4 q = {f2bf(b.x), f2bf(b.y), f2bf(b.z), f2bf(b.w)};
  *(ushort4*)(dst + i)     = p;
  *(ushort4*)(dst + i + 4) = q;
}

__global__ __launch_bounds__(256) void split_pair_kern(
    const float* __restrict__ src, unsigned short* __restrict__ hi,
    unsigned short* __restrict__ lo, int n)
{
  const int i = (blockIdx.x * 256 + threadIdx.x) * 4;
  if (i >= n) return;
  const float4 a = *(const float4*)(src + i);
  ushort4 h, l;
  split2(a.x, h.x, l.x); split2(a.y, h.y, l.y);
  split2(a.z, h.z, l.z); split2(a.w, h.w, l.w);
  *(ushort4*)(hi + i) = h;
  *(ushort4*)(lo + i) = l;
}

// ---------------------------------------------------------------------------
// positional bias (|i-j|), pre-scaled by log2e. grid = 16 (one per head).
// ---------------------------------------------------------------------------
__global__ __launch_bounds__(256) void pbias_kernel(
    const float* __restrict__ coeffs, const float* __restrict__ Wpos,
    float* __restrict__ pbias2)
{
  __shared__ float table[RESN][NFILT];
  const int h = blockIdx.x;
  const int tid = threadIdx.x;
  for (int rf = tid; rf < RESN * NFILT; rf += 256) {
    const int r = rf >> 2, f = rf & 3;
    const int tmax = r < (NTAPS - 1) ? r : (NTAPS - 1);
    float s = 0.f;
    for (int t = 0; t <= tmax; ++t)
      s += coeffs[f * NTAPS + t] * ((float)(r - t) * (1.0f / (float)(RESN - 1)));
    table[r][f] = s;
  }
  __syncthreads();
  float wp[NFILT];
#pragma unroll
  for (int f = 0; f < NFILT; ++f) wp[f] = Wpos[h * NFILT + f];
  for (int d = tid; d < SEQ; d += 256) {
    const float rel = (float)d / (float)(SEQ - 1);
    int idx = (int)rintf(rel * (float)(RESN - 1));
    idx = idx < 0 ? 0 : (idx > RESN - 1 ? RESN - 1 : idx);
    float s = 0.f;
#pragma unroll
    for (int f = 0; f < NFILT; ++f) s += table[idx][f] * wp[f];
    pbias2[h * SEQ + d] = s * LOG2E;
  }
}

// ---------------------------------------------------------------------------
// Pure-bf16 GEMM, 128x128, BK=32, double-buffered single-barrier (unchanged
// from R8 — improved then, don't churn blind). XCD swizzle.
// ---------------------------------------------------------------------------
__global__ __launch_bounds__(256, 4) void gemm_bf16(
    const unsigned short* __restrict__ A, const unsigned short* __restrict__ B,
    unsigned short* __restrict__ C, int M, int N, int K)
{
  __shared__ unsigned short As[2][128][32];
  __shared__ unsigned short Bs[2][128][32];
  const int tid = threadIdx.x;
  const int lane = tid & 63;
  const int w = tid >> 6, wm = w >> 1, wn = w & 1;
  const int c = lane & 15, G = lane >> 4;

  const int nwg = gridDim.x * gridDim.y;
  const int bid = blockIdx.y * gridDim.x + blockIdx.x;
  const int swz = (bid & 7) * (nwg >> 3) + (bid >> 3);
  const int bx = swz % gridDim.x, by = swz / gridDim.x;
  const int m0 = by * 128, n0 = bx * 128;

  const int srow = lane >> 2;
  const int scol = (lane & 3) << 3;
  const unsigned short* Ab = A + (size_t)m0 * K;
  const unsigned short* Bb = B + (size_t)n0 * K;

  f32x4 acc[4][4];
#pragma unroll
  for (int mf = 0; mf < 4; ++mf)
#pragma unroll
    for (int nf = 0; nf < 4; ++nf) acc[mf][nf] = (f32x4){0.f, 0.f, 0.f, 0.f};

  auto stage = [&](int buf, int k0) {
#pragma unroll
    for (int r = 0; r < 2; ++r) {
      const int chunk = r * 4 + w;
      const int row = (chunk << 4) + srow;
      async16(&As[buf][chunk << 4][0], Ab + (size_t)row * K + k0 + scol);
      async16(&Bs[buf][chunk << 4][0], Bb + (size_t)row * K + k0 + scol);
    }
  };

  stage(0, 0);
  __syncthreads();
  int cur = 0;
  const int NT = K >> 5;
  for (int t = 0; t < NT; ++t) {
    if (t + 1 < NT) stage(cur ^ 1, (t + 1) << 5);
    bf16x8 fa[4], fb[4];
#pragma unroll
    for (int mf = 0; mf < 4; ++mf)
      fa[mf] = *(const bf16x8*)&As[cur][wm * 64 + 16 * mf + c][8 * G];
#pragma unroll
    for (int nf = 0; nf < 4; ++nf)
      fb[nf] = *(const bf16x8*)&Bs[cur][wn * 64 + 16 * nf + c][8 * G];
#pragma unroll
    for (int nf = 0; nf < 4; ++nf)
#pragma unroll
      for (int mf = 0; mf < 4; ++mf)
        acc[mf][nf] = __builtin_amdgcn_mfma_f32_16x16x32_bf16(fa[mf], fb[nf], acc[mf][nf], 0, 0, 0);
    __syncthreads();
    cur ^= 1;
  }

#pragma unroll
  for (int mf = 0; mf < 4; ++mf)
#pragma unroll
    for (int nf = 0; nf < 4; ++nf)
#pragma unroll
      for (int r = 0; r < 4; ++r)
        C[(size_t)(m0 + wm * 64 + 16 * mf + 4 * G + r) * N + n0 + wn * 64 + 16 * nf + c] =
            f2bf(acc[mf][nf][r]);
}

// ---------------------------------------------------------------------------
// Split-bf16 (3-term) GEMM, 128x64 tile (grid 512 = 2/CU), BK=32, dbuf.
// Wave tile 64x32 -> 4x2 frags, 24 MFMA/K-step. LDS 48 KB.
// ---------------------------------------------------------------------------
__global__ __launch_bounds__(256, 4) void gemm_split3(
    const unsigned short* __restrict__ Ah, const unsigned short* __restrict__ Al,
    const unsigned short* __restrict__ Bh, const unsigned short* __restrict__ Bl,
    float* __restrict__ C, int M, int N, int K)
{
  __shared__ unsigned short AhS[2][128][32], AlS[2][128][32];
  __shared__ unsigned short BhS[2][64][32], BlS[2][64][32];
  const int tid = threadIdx.x;
  const int lane = tid & 63;
  const int w = tid >> 6, wm = w >> 1, wn = w & 1;
  const int c = lane & 15, G = lane >> 4;

  const int nwg = gridDim.x * gridDim.y;
  const int bid = blockIdx.y * gridDim.x + blockIdx.x;
  const int swz = (bid & 7) * (nwg >> 3) + (bid >> 3);
  const int bx = swz % gridDim.x, by = swz / gridDim.x;
  const int m0 = by * 128, n0 = bx * 64;

  const int srow = lane >> 2;            // 0..15
  const int scol = (lane & 3) << 3;      // 0,8,16,24

  f32x4 acc[4][2];
#pragma unroll
  for (int mf = 0; mf < 4; ++mf)
#pragma unroll
    for (int nf = 0; nf < 2; ++nf) acc[mf][nf] = (f32x4){0.f, 0.f, 0.f, 0.f};

  auto stage = [&](int buf, int k0) {
#pragma unroll
    for (int r = 0; r < 2; ++r) {
      const int rowA = r * 64 + 16 * w + srow;
      async16(&AhS[buf][r * 64 + 16 * w][0], Ah + (size_t)(m0 + rowA) * K + k0 + scol);
      async16(&AlS[buf][r * 64 + 16 * w][0], Al + (size_t)(m0 + rowA) * K + k0 + scol);
    }
    const int rowB = 16 * w + srow;
    async16(&BhS[buf][16 * w][0], Bh + (size_t)(n0 + rowB) * K + k0 + scol);
    async16(&BlS[buf][16 * w][0], Bl + (size_t)(n0 + rowB) * K + k0 + scol);
  };

  stage(0, 0);
  __syncthreads();
  int cur = 0;
  const int NT = K >> 5;
  for (int t = 0; t < NT; ++t) {
    if (t + 1 < NT) stage(cur ^ 1, (t + 1) << 5);
    bf16x8 fah[4], fal[4];
#pragma unroll
    for (int mf = 0; mf < 4; ++mf) {
      fah[mf] = *(const bf16x8*)&AhS[cur][64 * wm + 16 * mf + c][8 * G];
      fal[mf] = *(const bf16x8*)&AlS[cur][64 * wm + 16 * mf + c][8 * G];
    }
#pragma unroll
    for (int nf = 0; nf < 2; ++nf) {
      const bf16x8 fbh = *(const bf16x8*)&BhS[cur][32 * wn + 16 * nf + c][8 * G];
      const bf16x8 fbl = *(const bf16x8*)&BlS[cur][32 * wn + 16 * nf + c][8 * G];
#pragma unroll
      for (int mf = 0; mf < 4; ++mf) {
        acc[mf][nf] = __builtin_amdgcn_mfma_f32_16x16x32_bf16(fah[mf], fbh, acc[mf][nf], 0, 0, 0);
        acc[mf][nf] = __builtin_amdgcn_mfma_f32_16x16x32_bf16(fah[mf], fbl, acc[mf][nf], 0, 0, 0);
        acc[mf][nf] = __builtin_amdgcn_mfma_f32_16x16x32_bf16(fal[mf], fbh, acc[mf][nf], 0, 0, 0);
      }
    }
    __syncthreads();
    cur ^= 1;
  }

#pragma unroll
  for (int mf = 0; mf < 4; ++mf)
#pragma unroll
    for (int nf = 0; nf < 2; ++nf)
#pragma unroll
      for (int r = 0; r < 4; ++r)
        C[(size_t)(m0 + 64 * wm + 16 * mf + 4 * G + r) * N + n0 + 32 * wn + 16 * nf + c] =
            acc[mf][nf][r];
}

// ---------------------------------------------------------------------------
// Pure-bf16 MFMA flash attention.
// - P stays in REGISTERS: pkbf + v_permlane32/16_swap route A-fragments
//   (word0,2 = pl16(pl32(A0,B0)); word1,3 = pl16(pl32(A1,B1))).
// - pbias read direct from global (L1-resident 8KB/head); no pb LDS.
// - V^T swizzle includes d>>3: slot = g ^ (d&7) ^ (d>>3)  (8-way -> ~4-way wr).
// - defer-max: skip O-rescale when __all(rm <= mi + 8) (log2 domain).
// - XCD-chunked block swizzle: 4 heads per XCD, K/V L2-resident.
// LDS: K 8K + V 8K = 16 KB.
// ---------------------------------------------------------------------------
__global__ __launch_bounds__(256, 4) void attn_pure(
    const unsigned short* __restrict__ qkv,   // bf16 (4096,3072)
    const float* __restrict__ pbias2,         // (16,2048) f32, *log2e
    unsigned short* __restrict__ ao_hi,
    unsigned short* __restrict__ ao_lo)
{
  __shared__ unsigned short Kh[64][64];
  __shared__ unsigned short Vh[64][64];

  const int tid = threadIdx.x;
  const int lane = tid & 63;
  const int w = tid >> 6;
  const int c = lane & 15, G = lane >> 4;

  // XCD-chunked swizzle: contiguous 128-block chunks (4 heads) per XCD
  const int bid = blockIdx.y * gridDim.x + blockIdx.x;   // 0..1023
  const int swz = (bid & 7) * 128 + (bid >> 3);
  const int bh = swz >> 5, qblk = swz & 31;
  const int b = bh >> 4, h = bh & 15;
  const int i0 = qblk * 64;
  const int i_glob = i0 + w * 16 + c;
  const float scale2 = 0.125f * LOG2E;
  const float* pbh = pbias2 + h * SEQ;

  bf16x8 qb[2];
#pragma unroll
  for (int ks = 0; ks < 2; ++ks)
    qb[ks] = *(const bf16x8*)(qkv + (size_t)(b * SEQ + i_glob) * E3 + h * HDIM + 32 * ks + 8 * G);

  f32x4 oacc[4];
#pragma unroll
  for (int nf = 0; nf < 4; ++nf) oacc[nf] = (f32x4){0.f, 0.f, 0.f, 0.f};
  float mi = -1e30f, li = 0.f;

  const int vk  = tid & 7;              // V-stage: d-block index
  const int vd8 = 8 * vk;
  const int vjp = 2 * (tid >> 3);       // j-pair 0..62
  const int klrow = lane >> 3;
  const int klsl  = lane & 7;

  for (int jt = 0; jt < SEQ / 64; ++jt) {
    const int j0 = jt * 64;
    const size_t rowK = (size_t)(b * SEQ + j0) * E3 + DIMSZ + h * HDIM;
    const size_t rowV = (size_t)(b * SEQ + j0) * E3 + 2 * DIMSZ + h * HDIM;

    const bf16x8 v0 = *(const bf16x8*)(qkv + rowV + (size_t)vjp * E3 + vd8);
    const bf16x8 v1 = *(const bf16x8*)(qkv + rowV + (size_t)(vjp + 1) * E3 + vd8);

    __syncthreads();   // previous tile's LDS reads complete

    // K async stage (linear dest, pre-swizzled source: slot ^= row&7)
#pragma unroll
    for (int r = 0; r < 2; ++r) {
      const int chunk = r * 4 + w;
      const int krow = (chunk << 3) + klrow;
      const int ksl = klsl ^ (krow & 7);
      async16(&Kh[chunk << 3][0], qkv + rowK + (size_t)krow * E3 + 8 * ksl);
    }
    // V^T scatter (slot = g ^ e ^ k spreads banks across the 8 d-lanes)
#pragma unroll
    for (int e = 0; e < 8; ++e) {
      const int d = vd8 + e;
      const unsigned pk = (unsigned)(unsigned short)v0[e] |
                          ((unsigned)(unsigned short)v1[e] << 16);
      const int col = ((((vjp >> 3) ^ e ^ vk) & 7) << 3) | (vjp & 7);
      *(unsigned*)&Vh[d][col] = pk;
    }

    // bias values for this tile (global, L1-hot; independent of K/V)
    float pbv[16];
#pragma unroll
    for (int mf = 0; mf < 4; ++mf)
#pragma unroll
      for (int r = 0; r < 4; ++r) {
        const int j = j0 + 16 * mf + 4 * G + r;
        const int d = i_glob > j ? i_glob - j : j - i_glob;
        pbv[mf * 4 + r] = pbh[d];
      }

    __syncthreads();   // drains K gloads (vmcnt) + V writes

    // ---- S^T = K * Q^T ----
    f32x4 st[4];
#pragma unroll
    for (int mf = 0; mf < 4; ++mf) st[mf] = (f32x4){0.f, 0.f, 0.f, 0.f};
#pragma unroll
    for (int ks = 0; ks < 2; ++ks)
#pragma unroll
      for (int mf = 0; mf < 4; ++mf) {
        const int sr = (4 * ks + G) ^ (c & 7);
        const bf16x8 ka = *(const bf16x8*)&Kh[16 * mf + c][8 * sr];
        st[mf] = __builtin_amdgcn_mfma_f32_16x16x32_bf16(ka, qb[ks], st[mf], 0, 0, 0);
      }

    // ---- online softmax (exp2 domain, defer-max) ----
    float p[16];
    float rm = -1e30f;
#pragma unroll
    for (int t = 0; t < 16; ++t) {
      const float lg = fmaf(st[t >> 2][t & 3], scale2, pbv[t]);
      p[t] = lg;
      rm = fmaxf(rm, lg);
    }
    rm = fmaxf(rm, __shfl_xor(rm, 16));
    rm = fmaxf(rm, __shfl_xor(rm, 32));
    const bool skip = __all(rm <= mi + 8.f);
    if (!skip) {
      const float newm = fmaxf(mi, rm);
      const float fr = EXP2(mi - newm);
      mi = newm;
      float frr[4];
#pragma unroll
      for (int r = 0; r < 4; ++r) frr[r] = __shfl(fr, 20 * G + r);
#pragma unroll
      for (int nf = 0; nf < 4; ++nf)
#pragma unroll
        for (int r = 0; r < 4; ++r) oacc[nf][r] *= frr[r];
      li *= fr;
    }
    float rs = 0.f;
#pragma unroll
    for (int t = 0; t < 16; ++t) {
      p[t] = EXP2(p[t] - mi);
      rs += p[t];
    }
    rs += __shfl_xor(rs, 16);
    rs += __shfl_xor(rs, 32);
    li += rs;

    // ---- P -> A-fragments fully in-register (cvt_pk + permlane swaps) ----
    bf16x8 pa[2];
#pragma unroll
    for (int ks = 0; ks < 2; ++ks) {
      unsigned a0 = pkbf(p[8 * ks + 0], p[8 * ks + 1]);
      unsigned a1 = pkbf(p[8 * ks + 2], p[8 * ks + 3]);
      unsigned b0 = pkbf(p[8 * ks + 4], p[8 * ks + 5]);
      unsigned b1 = pkbf(p[8 * ks + 6], p[8 * ks + 7]);
      asm("v_permlane32_swap_b32 %0, %1" : "+v"(a0), "+v"(b0));
      asm("v_permlane16_swap_b32 %0, %1" : "+v"(a0), "+v"(b0));
      asm("v_permlane32_swap_b32 %0, %1" : "+v"(a1), "+v"(b1));
      asm("v_permlane16_swap_b32 %0, %1" : "+v"(a1), "+v"(b1));
      union { unsigned u[4]; bf16x8 v; } pw;
      pw.u[0] = a0; pw.u[1] = a1; pw.u[2] = b0; pw.u[3] = b1;
      pa[ks] = pw.v;
    }

    // ---- O += P V ----
#pragma unroll
    for (int ks = 0; ks < 2; ++ks)
#pragma unroll
      for (int nf = 0; nf < 4; ++nf) {
        const int d = 16 * nf + c;
        const int sv = (4 * ks + G) ^ (c & 7) ^ ((2 * nf + (c >> 3)) & 7);
        const bf16x8 vb = *(const bf16x8*)&Vh[d][8 * sv];
        oacc[nf] = __builtin_amdgcn_mfma_f32_16x16x32_bf16(pa[ks], vb, oacc[nf], 0, 0, 0);
      }
  }

  float rinv[4];
#pragma unroll
  for (int r = 0; r < 4; ++r) rinv[r] = 1.0f / __shfl(li, 20 * G + r);
#pragma unroll
  for (int nf = 0; nf < 4; ++nf)
#pragma unroll
    for (int r = 0; r < 4; ++r) {
      const float v = oacc[nf][r] * rinv[r];
      const size_t off = (size_t)(b * SEQ + i0 + 16 * w + 4 * G + r) * DIMSZ +
                         h * HDIM + 16 * nf + c;
      unsigned short vh, vl;
      split2(v, vh, vl);
      ao_hi[off] = vh;
      ao_lo[off] = vl;
    }
}

// ---------------------------------------------------------------------------
extern "C" void kernel_launch(void* const* d_in, const int* in_sizes, int n_in,
                              void* d_out, int out_size, void* d_ws, size_t ws_size,
                              hipStream_t stream) {
  const float* x      = (const float*)d_in[0];
  const float* Wqkv   = (const float*)d_in[1];
  const float* Wout   = (const float*)d_in[2];
  const float* Wpos   = (const float*)d_in[3];
  const float* coeffs = (const float*)d_in[4];
  float* out = (float*)d_out;

  unsigned short* qkv_bf  = (unsigned short*)d_ws;           // 4096*3072
  unsigned short* x_bf    = qkv_bf + (size_t)MROWS * E3;     // 4096*1024
  unsigned short* wqkv_bf = x_bf + (size_t)MROWS * DIMSZ;    // 3072*1024
  unsigned short* wout_h  = wqkv_bf + (size_t)E3 * DIMSZ;    // 1024*1024
  unsigned short* wout_l  = wout_h + (size_t)DIMSZ * DIMSZ;
  unsigned short* ao_h    = wout_l + (size_t)DIMSZ * DIMSZ;  // 4096*1024
  unsigned short* ao_l    = ao_h + (size_t)MROWS * DIMSZ;
  float* pbias2 = (float*)(ao_l + (size_t)MROWS * DIMSZ);    // 16*2048

  const int nx = MROWS * DIMSZ;
  const int nw = E3 * DIMSZ;
  const int no = DIMSZ * DIMSZ;

  cvt_bf16_kern<<<nx / 2048, 256, 0, stream>>>(x, x_bf, nx);
  cvt_bf16_kern<<<nw / 2048, 256, 0, stream>>>(Wqkv, wqkv_bf, nw);
  split_pair_kern<<<no / 1024, 256, 0, stream>>>(Wout, wout_h, wout_l, no);
  pbias_kernel<<<HEADS, 256, 0, stream>>>(coeffs, Wpos, pbias2);

  dim3 g1(E3 / 128, MROWS / 128);      // 768 blocks
  gemm_bf16<<<g1, 256, 0, stream>>>(x_bf, wqkv_bf, qkv_bf, MROWS, E3, DIMSZ);

  dim3 g2(SEQ / 64, BATCH * HEADS);    // 1024 blocks
  attn_pure<<<g2, 256, 0, stream>>>(qkv_bf, pbias2, ao_h, ao_l);

  dim3 g3(DIMSZ / 64, MROWS / 128);    // 16 x 32 = 512 blocks
  gemm_split3<<<g3, 256, 0, stream>>>(ao_h, ao_l, wout_h, wout_l, out, MROWS, DIMSZ, DIMSZ);
}